// Round 1
// baseline (185.525 us; speedup 1.0000x reference)
//
#include <hip/hip_runtime.h>
#include <stdint.h>

// Threefry-2x32, 20 rounds (Random123 / JAX threefry2x32_p).
__device__ __forceinline__ void tf2x32(uint32_t k0, uint32_t k1,
                                       uint32_t x0, uint32_t x1,
                                       uint32_t& o0, uint32_t& o1) {
  const uint32_t ks2 = k0 ^ k1 ^ 0x1BD11BDAu;
  x0 += k0; x1 += k1;
#define TF_R(r) { x0 += x1; x1 = (x1 << (r)) | (x1 >> (32 - (r))); x1 ^= x0; }
  TF_R(13) TF_R(15) TF_R(26) TF_R(6)
  x0 += k1; x1 += ks2 + 1u;
  TF_R(17) TF_R(29) TF_R(16) TF_R(24)
  x0 += ks2; x1 += k0 + 2u;
  TF_R(13) TF_R(15) TF_R(26) TF_R(6)
  x0 += k0; x1 += k1 + 3u;
  TF_R(17) TF_R(29) TF_R(16) TF_R(24)
  x0 += k1; x1 += ks2 + 4u;
  TF_R(13) TF_R(15) TF_R(26) TF_R(6)
  x0 += ks2; x1 += k0 + 5u;
#undef TF_R
  o0 = x0; o1 = x1;
}

#define MAXF 1024

// Partitionable-threefry mode (JAX >= 0.5 default):
//   fold_in(key, i)      = tf(key, (0, i))            -> full pair is new key
//   split(key)[j]        = tf(key, (0, j))            -> full pair is key j
//   random_bits32(key)[j] = o0 ^ o1 of tf(key, (0, j))
__global__ __launch_bounds__(256) void hmm_kernel(
    const float* __restrict__ initial,
    const float* __restrict__ initial_trans,
    const int* __restrict__ n_frames_p,
    float* __restrict__ out,
    int N) {
  __shared__ uint32_t s_ku0[MAXF];
  __shared__ uint32_t s_ku1[MAXF];
  __shared__ float    s_p[MAXF];

  const int nf = n_frames_p[0];
  const float trans = initial_trans[0];

  // Per-frame schedule: ku (uniform key) and p (switch probability).
  for (int i = threadIdx.x; i < nf && i < MAXF; i += blockDim.x) {
    uint32_t f0, f1, t0, t1;
    // key_i = fold_in(key(42), i); base key data = (0, 42)
    tf2x32(0u, 42u, 0u, (uint32_t)i, f0, f1);
    // ku, kr = split(key_i): ku = tf(key_i,(0,0)), kr = tf(key_i,(0,1))
    tf2x32(f0, f1, 0u, 0u, t0, t1);
    s_ku0[i] = t0; s_ku1[i] = t1;

    // p refreshed at frames j = 100*floor(i/100) via randint(kr_j, (), 1, 10)
    const int jf = i - (i % 100);
    uint32_t g0, g1, kr0, kr1, a0, a1, b0, b1, h0, h1, l0, l1;
    tf2x32(0u, 42u, 0u, (uint32_t)jf, g0, g1);       // key_jf
    tf2x32(g0, g1, 0u, 1u, kr0, kr1);                // kr_jf = split[1]
    // randint: k1, k2 = split(kr); hb = bits32(k1,()), lb = bits32(k2,())
    tf2x32(kr0, kr1, 0u, 0u, a0, a1);                // k1
    tf2x32(kr0, kr1, 0u, 1u, b0, b1);                // k2
    tf2x32(a0, a1, 0u, 0u, h0, h1);
    tf2x32(b0, b1, 0u, 0u, l0, l1);
    const uint32_t hb = h0 ^ h1, lb = l0 ^ l1;
    // span=9, multiplier=(2^16 % 9)^2 % 9 = 4
    const uint32_t off = ((hb % 9u) * 4u + (lb % 9u)) % 9u;
    s_p[i] = trans * (float)(1u + off);
  }
  __syncthreads();

  const int n = blockIdx.x * blockDim.x + threadIdx.x;
  if (n >= N) return;

  // state index s: initial one-hot [N,2]; s=0 means state vector (1,0)
  int s = (initial[2 * n] < 0.5f) ? 1 : 0;
  float* o = out + n;

  for (int i = 0; i < nf; ++i) {
    const uint32_t ku0 = s_ku0[i], ku1 = s_ku1[i];
    const float p = s_p[i];
    // uniform element j = 2n + s of shape (N,2): bits = o0^o1 of tf(ku,(0,j))
    uint32_t o0, o1;
    tf2x32(ku0, ku1, 0u, (uint32_t)(2 * n + s), o0, o1);
    const uint32_t bits = o0 ^ o1;
    const float u = __uint_as_float((bits >> 9) | 0x3f800000u) - 1.0f;
    const float thr = s ? p : 0.5f;   // row 0: P(draw 1)=0.5 ; row 1: P(draw 1)=p
    s ^= (u < thr) ? 1 : 0;           // category 1 -> swap transition
    o[(size_t)i * N] = s ? 0.0f : 1.0f;  // chain[i] = state[:,0]
  }
}

extern "C" void kernel_launch(void* const* d_in, const int* in_sizes, int n_in,
                              void* d_out, int out_size, void* d_ws, size_t ws_size,
                              hipStream_t stream) {
  const float* initial = (const float*)d_in[0];
  // d_in[1] = transition_matrix: constant identity/swap, folded into bit-flip logic
  const float* initial_trans = (const float*)d_in[2];
  const int* n_frames = (const int*)d_in[3];
  float* out = (float*)d_out;

  const int N = in_sizes[0] / 2;  // 100000
  const int block = 256;
  const int grid = (N + block - 1) / block;
  hipLaunchKernelGGL(hmm_kernel, dim3(grid), dim3(block), 0, stream,
                     initial, initial_trans, n_frames, out, N);
}

// Round 2
// 146.607 us; speedup vs baseline: 1.2655x; 1.2655x over previous
//
#include <hip/hip_runtime.h>
#include <stdint.h>

// Threefry-2x32, 20 rounds (Random123 / JAX threefry2x32_p).
__device__ __forceinline__ void tf2x32(uint32_t k0, uint32_t k1,
                                       uint32_t x0, uint32_t x1,
                                       uint32_t& o0, uint32_t& o1) {
  const uint32_t ks2 = k0 ^ k1 ^ 0x1BD11BDAu;
  x0 += k0; x1 += k1;
#define TF_R(r) { x0 += x1; x1 = __builtin_rotateleft32(x1, (r)); x1 ^= x0; }
  TF_R(13) TF_R(15) TF_R(26) TF_R(6)
  x0 += k1; x1 += ks2 + 1u;
  TF_R(17) TF_R(29) TF_R(16) TF_R(24)
  x0 += ks2; x1 += k0 + 2u;
  TF_R(13) TF_R(15) TF_R(26) TF_R(6)
  x0 += k0; x1 += k1 + 3u;
  TF_R(17) TF_R(29) TF_R(16) TF_R(24)
  x0 += k1; x1 += ks2 + 4u;
  TF_R(13) TF_R(15) TF_R(26) TF_R(6)
  x0 += ks2; x1 += k0 + 5u;
#undef TF_R
  o0 = x0; o1 = x1;
}

#define LCHUNK 100   // frames per chunk (matches p-refresh period)
#define LMAX   128   // LDS schedule capacity per block
#define F0     8     // unconditional both-chain warmup frames

// Pass 1: each (particle, chunk) thread runs its chunk.
//   chunk 0: true chain from the real initial state.
//   chunk c>0: speculative chains from both entry states; they couple
//   (merge) w.p. 1/2 per frame and stay merged (same RNG element).
//   Writes chain-A (entry state 0) output; records finals + merge frame.
__global__ __launch_bounds__(256) void hmm_main(
    const float* __restrict__ initial,
    const float* __restrict__ initial_trans,
    float* __restrict__ out,
    uint32_t* __restrict__ ws,
    int N, int nf) {
  __shared__ uint32_t s_ku0[LMAX], s_ku1[LMAX], s_thr[LMAX];
  const int c = blockIdx.y;
  const int c0 = c * LCHUNK;
  const int Leff = min(LCHUNK, nf - c0);
  const float trans = initial_trans[0];

  // Per-frame schedule for this chunk: uniform key (ku) and integer
  // threshold thr32 = ceil(p * 2^23) << 9 so that (u < p) == (bits < thr32).
  for (int i = threadIdx.x; i < Leff; i += blockDim.x) {
    const int gi = c0 + i;
    uint32_t f0_, f1_, t0, t1;
    tf2x32(0u, 42u, 0u, (uint32_t)gi, f0_, f1_);        // fold_in(key(42), gi)
    tf2x32(f0_, f1_, 0u, 0u, t0, t1);                   // ku = split[0]
    s_ku0[i] = t0; s_ku1[i] = t1;
    const int jf = gi - (gi % 100);                     // p refresh anchor
    uint32_t g0, g1, kr0, kr1, a0, a1, b0, b1, h0, h1, l0, l1;
    tf2x32(0u, 42u, 0u, (uint32_t)jf, g0, g1);
    tf2x32(g0, g1, 0u, 1u, kr0, kr1);                   // kr = split[1]
    tf2x32(kr0, kr1, 0u, 0u, a0, a1);                   // randint: k1
    tf2x32(kr0, kr1, 0u, 1u, b0, b1);                   //          k2
    tf2x32(a0, a1, 0u, 0u, h0, h1);
    tf2x32(b0, b1, 0u, 0u, l0, l1);
    const uint32_t hb = h0 ^ h1, lb = l0 ^ l1;
    const uint32_t off = ((hb % 9u) * 4u + (lb % 9u)) % 9u;  // span 9, mult 4
    const float p = trans * (float)(1u + off);
    const uint32_t mant = (uint32_t)ceilf(p * 8388608.0f);   // exact: *2^23
    s_thr[i] = mant << 9;
  }
  __syncthreads();

  const int n = blockIdx.x * blockDim.x + threadIdx.x;
  if (n >= N || Leff <= 0) return;
  const uint32_t twon = 2u * (uint32_t)n;
  float* o = out + (size_t)c0 * N + n;

  uint32_t sA, sB, mf = 0;
  if (c == 0) {
    sA = (initial[2 * n] < 0.5f) ? 1u : 0u;
    sB = sA;
  } else {
    sA = 0u; sB = 1u;
  }

  int f = 0;
  if (c != 0) {
    // Warmup: both chains unconditionally (ILP-2, no divergence).
    // Correct even if already merged (merged chains get identical updates).
    for (; f < F0 && f < Leff; ++f) {
      const uint32_t ku0 = s_ku0[f], ku1 = s_ku1[f], tp = s_thr[f];
      uint32_t a0, a1, b0, b1;
      tf2x32(ku0, ku1, 0u, twon, a0, a1);        // element for state 0
      tf2x32(ku0, ku1, 0u, twon + 1u, b0, b1);   // element for state 1
      const uint32_t flip0 = ((a0 ^ a1) < 0x80000000u) ? 1u : 0u;
      const uint32_t flip1 = ((b0 ^ b1) < tp) ? 1u : 0u;
      sA = sA ? (1u ^ flip1) : flip0;
      sB = sB ? (1u ^ flip1) : flip0;
      mf += (sA != sB) ? 1u : 0u;
      o[(size_t)f * N] = sA ? 0.0f : 1.0f;
    }
  }
  for (; f < Leff; ++f) {
    const uint32_t ku0 = s_ku0[f], ku1 = s_ku1[f], tp = s_thr[f];
    if (sA != sB) {
      uint32_t a0, a1, b0, b1;
      tf2x32(ku0, ku1, 0u, twon, a0, a1);
      tf2x32(ku0, ku1, 0u, twon + 1u, b0, b1);
      const uint32_t flip0 = ((a0 ^ a1) < 0x80000000u) ? 1u : 0u;
      const uint32_t flip1 = ((b0 ^ b1) < tp) ? 1u : 0u;
      sA = sA ? (1u ^ flip1) : flip0;
      sB = sB ? (1u ^ flip1) : flip0;
    } else {
      uint32_t a0, a1;
      tf2x32(ku0, ku1, 0u, twon + sA, a0, a1);
      const uint32_t thr = sA ? tp : 0x80000000u;
      sA ^= ((a0 ^ a1) < thr) ? 1u : 0u;
      sB = sA;
    }
    mf += (sA != sB) ? 1u : 0u;
    o[(size_t)f * N] = sA ? 0.0f : 1.0f;
  }
  // finals for both entry states + count of pre-merge (differing) frames
  ws[(size_t)c * N + n] = sA | (sB << 1) | (mf << 2);
}

// Pass 2: per particle, compose chunk finals; where the true entry state
// of a speculative chunk was 1, flip the pre-merge output rows (chain B's
// pre-merge outputs are exactly 1 - chain A's).
__global__ __launch_bounds__(256) void hmm_fix(
    const float* __restrict__ initial,
    float* __restrict__ out,
    const uint32_t* __restrict__ ws,
    int N, int C) {
  const int n = blockIdx.x * blockDim.x + threadIdx.x;
  if (n >= N) return;
  uint32_t s = (initial[2 * n] < 0.5f) ? 1u : 0u;
  for (int c = 0; c < C; ++c) {
    const uint32_t w = ws[(size_t)c * N + n];
    if (c > 0 && s == 1u) {
      const int c0 = c * LCHUNK;
      const int mf = (int)(w >> 2);
      for (int f = 0; f < mf; ++f) {
        float* q = out + (size_t)(c0 + f) * N + n;
        *q = 1.0f - *q;
      }
    }
    s = (s == 0u) ? (w & 1u) : ((w >> 1) & 1u);
  }
}

extern "C" void kernel_launch(void* const* d_in, const int* in_sizes, int n_in,
                              void* d_out, int out_size, void* d_ws, size_t ws_size,
                              hipStream_t stream) {
  const float* initial = (const float*)d_in[0];
  // d_in[1] = transition_matrix: constant identity/swap, folded into bit-flip
  const float* initial_trans = (const float*)d_in[2];
  float* out = (float*)d_out;

  const int N = in_sizes[0] / 2;          // 100000
  const int nf = out_size / N;            // 500
  const int C = (nf + LCHUNK - 1) / LCHUNK;
  const int gx = (N + 255) / 256;

  hipLaunchKernelGGL(hmm_main, dim3(gx, C), dim3(256), 0, stream,
                     initial, initial_trans, out, (uint32_t*)d_ws, N, nf);
  hipLaunchKernelGGL(hmm_fix, dim3(gx), dim3(256), 0, stream,
                     initial, out, (uint32_t*)d_ws, N, C);
}

// Round 4
// 135.561 us; speedup vs baseline: 1.3686x; 1.0815x over previous
//
#include <hip/hip_runtime.h>
#include <stdint.h>

// Threefry-2x32, 20 rounds (Random123 / JAX threefry2x32_p).
__device__ __forceinline__ void tf2x32(uint32_t k0, uint32_t k1,
                                       uint32_t x0, uint32_t x1,
                                       uint32_t& o0, uint32_t& o1) {
  const uint32_t ks2 = k0 ^ k1 ^ 0x1BD11BDAu;
  x0 += k0; x1 += k1;
#define TF_R(r) { x0 += x1; x1 = __builtin_rotateleft32(x1, (r)); x1 ^= x0; }
  TF_R(13) TF_R(15) TF_R(26) TF_R(6)
  x0 += k1; x1 += ks2 + 1u;
  TF_R(17) TF_R(29) TF_R(16) TF_R(24)
  x0 += ks2; x1 += k0 + 2u;
  TF_R(13) TF_R(15) TF_R(26) TF_R(6)
  x0 += k0; x1 += k1 + 3u;
  TF_R(17) TF_R(29) TF_R(16) TF_R(24)
  x0 += k1; x1 += ks2 + 4u;
  TF_R(13) TF_R(15) TF_R(26) TF_R(6)
  x0 += ks2; x1 += k0 + 5u;
#undef TF_R
  o0 = x0; o1 = x1;
}

#define LCHUNK 100   // frames per chunk (matches p-refresh period)
#define F0     8     // unconditional both-chain warmup frames

// Kernel 0: per-frame schedule {ku0, ku1, thr32} -> uint4 table in ws.
// thr32 = ceil(p * 2^23) << 9 so that (uniform(u) < p) == (bits < thr32).
__global__ __launch_bounds__(256) void hmm_sched(
    const float* __restrict__ initial_trans,
    uint4* __restrict__ sched, int nf) {
  const int gi = blockIdx.x * blockDim.x + threadIdx.x;
  if (gi >= nf) return;
  const float trans = initial_trans[0];
  uint32_t f0_, f1_, t0, t1;
  tf2x32(0u, 42u, 0u, (uint32_t)gi, f0_, f1_);        // fold_in(key(42), gi)
  tf2x32(f0_, f1_, 0u, 0u, t0, t1);                   // ku = split[0]
  const int jf = gi - (gi % 100);                     // p refresh anchor
  uint32_t g0, g1, kr0, kr1, a0, a1, b0, b1, h0, h1, l0, l1;
  tf2x32(0u, 42u, 0u, (uint32_t)jf, g0, g1);
  tf2x32(g0, g1, 0u, 1u, kr0, kr1);                   // kr = split[1]
  tf2x32(kr0, kr1, 0u, 0u, a0, a1);                   // randint: k1
  tf2x32(kr0, kr1, 0u, 1u, b0, b1);                   //          k2
  tf2x32(a0, a1, 0u, 0u, h0, h1);
  tf2x32(b0, b1, 0u, 0u, l0, l1);
  const uint32_t hb = h0 ^ h1, lb = l0 ^ l1;
  const uint32_t off = ((hb % 9u) * 4u + (lb % 9u)) % 9u;  // span 9, mult 4
  const float p = trans * (float)(1u + off);
  const uint32_t mant = (uint32_t)ceilf(p * 8388608.0f);
  sched[gi] = make_uint4(t0, t1, mant << 9, 0u);
}

// Both-chain update for one particle; returns 1 if chains still differ.
__device__ __forceinline__ uint32_t bothstep(uint32_t k0, uint32_t k1,
                                             uint32_t tp, uint32_t twon,
                                             uint32_t& sA, uint32_t& sB) {
  uint32_t a0, a1, b0, b1;
  tf2x32(k0, k1, 0u, twon, a0, a1);          // element for state 0
  tf2x32(k0, k1, 0u, twon + 1u, b0, b1);     // element for state 1
  const uint32_t flip0 = ((a0 ^ a1) < 0x80000000u) ? 1u : 0u;
  const uint32_t flip1 = ((b0 ^ b1) < tp) ? 1u : 0u;
  sA = sA ? (1u ^ flip1) : flip0;
  sB = sB ? (1u ^ flip1) : flip0;
  return (sA != sB) ? 1u : 0u;
}

// Merged single-chain update.
__device__ __forceinline__ void mstep(uint32_t k0, uint32_t k1, uint32_t tp,
                                      uint32_t twon, uint32_t& s) {
  uint32_t a0, a1;
  tf2x32(k0, k1, 0u, twon + s, a0, a1);
  const uint32_t thr = s ? tp : 0x80000000u;
  s ^= ((a0 ^ a1) < thr) ? 1u : 0u;
}

// Kernel 1: each thread owns TWO particles (2n, 2n+1) for one frame chunk.
// chunk 0 runs the true chain; chunks c>0 run both entry states until the
// chains couple (merge), then a single merged chain. float2 coalesced output.
__global__ __launch_bounds__(256) void hmm_main(
    const float* __restrict__ initial,
    const uint4* __restrict__ sched,
    float* __restrict__ out,
    uint32_t* __restrict__ fin,
    int N, int nf) {
  const int t = blockIdx.x * blockDim.x + threadIdx.x;
  const int n0 = 2 * t;
  if (n0 >= N) return;
  const int c = blockIdx.y;
  const int c0 = c * LCHUNK;
  const int Leff = min(LCHUNK, nf - c0);
  if (Leff <= 0) return;

  const uint4* __restrict__ sch = sched + c0;   // block-uniform -> s_load
  const uint32_t twon0 = 2u * (uint32_t)n0;
  const uint32_t twon1 = twon0 + 2u;
  float2* o = (float2*)(out + (size_t)c0 * N + n0);
  const int ostr = N >> 1;   // float2 stride per frame

  uint32_t s0A, s0B, s1A, s1B, mf0 = 0, mf1 = 0;
  int f = 0;

  if (c == 0) {
    const float4 iv = *(const float4*)(initial + 2 * n0);  // [p0s0,p0s1,p1s0,p1s1]
    s0A = (iv.x < 0.5f) ? 1u : 0u;  s0B = s0A;
    s1A = (iv.z < 0.5f) ? 1u : 0u;  s1B = s1A;
  } else {
    s0A = 0u; s0B = 1u; s1A = 0u; s1B = 1u;
    // Warmup + couple phase: both chains for both particles (no per-lane
    // branch; merged lanes compute identical updates). Exit is wave-uniform:
    // break only when EVERY lane's particles have coupled (sA==sB).
    uint32_t d = 1u;
    for (; f < Leff; ++f) {
      if (f >= F0 && !__any((int)d)) break;
      const uint4 sc = sch[f];
      const uint32_t d0 = bothstep(sc.x, sc.y, sc.z, twon0, s0A, s0B);
      const uint32_t d1 = bothstep(sc.x, sc.y, sc.z, twon1, s1A, s1B);
      mf0 += d0; mf1 += d1; d = d0 | d1;
      *o = make_float2(s0A ? 0.0f : 1.0f, s1A ? 0.0f : 1.0f);
      o += ostr;
    }
  }
  const int fm = f;  // frame index at merged-loop entry
  // Merged steady-state loop: one threefry per particle per frame.
  for (; f < Leff; ++f) {
    const uint4 sc = sch[f];
    mstep(sc.x, sc.y, sc.z, twon0, s0A);
    mstep(sc.x, sc.y, sc.z, twon1, s1A);
    *o = make_float2(s0A ? 0.0f : 1.0f, s1A ? 0.0f : 1.0f);
    o += ostr;
  }
  // If the merged loop ran (c==0 always; c>0 only after the wave-uniform
  // break, which requires ALL particles coupled), chain B's final tracks
  // chain A. If the couple phase ran the whole chunk (fm==Leff), sB is the
  // live un-coupled value and must be preserved.
  if (fm < Leff) { s0B = s0A; s1B = s1A; }
  // finals for both entry states + count of pre-merge (differing) frames
  *(uint2*)(fin + (size_t)c * N + n0) =
      make_uint2(s0A | (s0B << 1) | (mf0 << 2), s1A | (s1B << 1) | (mf1 << 2));
}

// Kernel 2: per particle, compose chunk finals; where the true entry state
// of a speculative chunk was 1, flip the pre-merge output rows (chain B's
// pre-merge outputs are exactly 1 - chain A's).
__global__ __launch_bounds__(256) void hmm_fix(
    const float* __restrict__ initial,
    float* __restrict__ out,
    const uint32_t* __restrict__ fin,
    int N, int C) {
  const int n = blockIdx.x * blockDim.x + threadIdx.x;
  if (n >= N) return;
  uint32_t s = (initial[2 * n] < 0.5f) ? 1u : 0u;
  for (int c = 0; c < C; ++c) {
    const uint32_t w = fin[(size_t)c * N + n];
    if (c > 0 && s == 1u) {
      const int c0 = c * LCHUNK;
      const int mf = (int)(w >> 2);
      for (int f = 0; f < mf; ++f) {
        float* q = out + (size_t)(c0 + f) * N + n;
        *q = 1.0f - *q;
      }
    }
    s = (s == 0u) ? (w & 1u) : ((w >> 1) & 1u);
  }
}

extern "C" void kernel_launch(void* const* d_in, const int* in_sizes, int n_in,
                              void* d_out, int out_size, void* d_ws, size_t ws_size,
                              hipStream_t stream) {
  const float* initial = (const float*)d_in[0];
  // d_in[1] = transition_matrix: constant identity/swap, folded into bit-flip
  const float* initial_trans = (const float*)d_in[2];
  float* out = (float*)d_out;

  const int N = in_sizes[0] / 2;          // 100000
  const int nf = out_size / N;            // 500
  const int C = (nf + LCHUNK - 1) / LCHUNK;

  uint4* sched = (uint4*)d_ws;
  const size_t finoff = (((size_t)nf * 16) + 511) & ~(size_t)511;
  uint32_t* fin = (uint32_t*)((char*)d_ws + finoff);

  hipLaunchKernelGGL(hmm_sched, dim3((nf + 255) / 256), dim3(256), 0, stream,
                     initial_trans, sched, nf);
  const int gx = (N / 2 + 255) / 256;
  hipLaunchKernelGGL(hmm_main, dim3(gx, C), dim3(256), 0, stream,
                     initial, sched, out, fin, N, nf);
  hipLaunchKernelGGL(hmm_fix, dim3((N + 255) / 256), dim3(256), 0, stream,
                     initial, out, fin, N, C);
}